// Round 21
// baseline (884.789 us; speedup 1.0000x reference)
//
#include <hip/hip_runtime.h>

// B=8192, S=100, H=512, NF=50 filled/spin. out[b] = det_up * det_dn.
//   k_prep  : W2 -> fp16 fragment-image [spin][ntile64][kc][ko][64][8] (unscaled)
//   k_hidden: h rows -> single fp16 fragment-image slab (x256) + rank8
//   k_gemm  : 256x64 block tile, wave 64x64, acc[2][2], 1-product fp16 MFMA,
//             direct global->VGPR fragments, no LDS/barriers, unroll 4.
//   k_det   : 50x50 LU, 1 matrix/wave, rcpf, readlane broadcasts BATCHED in
//             groups of 16 (round-21: v_readlane writes an SGPR; a VALU reader
//             within ~5 cycles stalls. The rl,fma,rl,fma pattern paid ~4 dead
//             cycles per element pair = the 2.4x VALU inflation that was
//             insensitive to every register/occupancy knob in R16-R20).
// mats layout: row stride 52 floats, matrix stride 2600.

#define B_   8192
#define S_   100
#define H_   512
#define NF   50
#define W2N  5000
#define NTB  79            // 64-col tiles over 5000 (+56 pad)
#define MROW 52
#define MMAT 2600
#define SCALE_H 256.0f

typedef _Float16 half8 __attribute__((ext_vector_type(8)));
typedef float f32x16 __attribute__((ext_vector_type(16)));
typedef unsigned short u16;
typedef unsigned int u32;

__device__ __forceinline__ u16 f2h(float x) {
  _Float16 h = (_Float16)x;
  return __builtin_bit_cast(u16, h);
}
__device__ __forceinline__ float rlane(float x, int sl) {
  return __builtin_bit_cast(float,
      __builtin_amdgcn_readlane(__builtin_bit_cast(int, x), sl));
}

// ---- K0: W2 -> w2t[spin][n][kc][ko][64][8] fp16, cols >=5000 zero ----
__global__ void k_prep(const float* __restrict__ W2u, const float* __restrict__ W2d,
                       u16* __restrict__ w2t) {
  __shared__ float sT[16][65];
  int n = blockIdx.x, kc = blockIdx.y, spin = blockIdx.z, t = threadIdx.x;
  const float* W2 = spin ? W2d : W2u;
  #pragma unroll
  for (int i = 0; i < 4; ++i) {
    int idx = i * 256 + t;
    int r = idx >> 6, c = idx & 63;
    int nc = n * 64 + c;
    sT[r][c] = (nc < W2N) ? W2[(size_t)(kc * 16 + r) * W2N + nc] : 0.f;
  }
  __syncthreads();
  if (t < 128) {
    int ko = t >> 6, c = t & 63;
    __align__(16) u16 hb[8];
    #pragma unroll
    for (int j = 0; j < 8; ++j) hb[j] = f2h(sT[ko * 8 + j][c]);
    u16* dst = w2t + (((size_t)spin * NTB + n) * 32 + kc) * 1024 +
               (ko * 64 + c) * 8;
    *(uint4*)dst = *(const uint4*)&hb[0];
  }
}

// ---- K1: ballot-rank + h = relu(sum W1 rows + b1) -> fp16 slab + rank8 ----
__global__ void k_hidden(const float* __restrict__ cfg, const float* __restrict__ W1u,
                         const float* __restrict__ b1u, const float* __restrict__ W1d,
                         const float* __restrict__ b1d, u16* __restrict__ hk_h,
                         signed char* __restrict__ rank8) {
  __shared__ int sFilled[NF];
  __shared__ unsigned long long sM0;
  __shared__ u16 sHv[512];
  int b = blockIdx.x, spin = blockIdx.y, t = threadIdx.x;
  const float* W1 = spin ? W1d : W1u;
  const float* b1 = spin ? b1d : b1u;
  bool f = (t < S_) ? (cfg[(size_t)b * 200 + spin * 100 + t] > 0.5f) : false;
  unsigned long long m = __ballot(f);
  if (t == 0) sM0 = m;
  __syncthreads();
  int r = -1;
  if (f) {
    int lane = t & 63;
    int below = __popcll(m & ((1ULL << lane) - 1ULL));
    r = (t < 64) ? below : (__popcll(sM0) + below);
    sFilled[r] = t;
  }
  if (t < S_) rank8[((size_t)spin * B_ + b) * S_ + t] = (signed char)r;
  __syncthreads();
  float a0 = b1[t], a1 = b1[t + 256];
  #pragma unroll 5
  for (int i = 0; i < NF; ++i) {
    const float* w = W1 + (size_t)sFilled[i] * H_;
    a0 += w[t];
    a1 += w[t + 256];
  }
  a0 = fmaxf(a0, 0.f) * SCALE_H;
  a1 = fmaxf(a1, 0.f) * SCALE_H;
  sHv[t] = f2h(a0);
  sHv[t + 256] = f2h(a1);
  __syncthreads();
  int mtile = b >> 8, rr = b & 255;
  if (t < 64) {
    int kc = t >> 1, ko = t & 1;       // k-octet t of 64
    size_t off = ((((size_t)spin * 32 + mtile) * 32 + kc) * 2 + ko) * 2048 + rr * 8;
    *(uint4*)(hk_h + off) = *(const uint4*)&sHv[t * 8];
  }
}

// ---- K2: dense 256x64 GEMM, 1-product fp16, direct global->VGPR fragments ----
// grid (32 mtile, 79 ntile), block 256 = 4 waves stacked in M. acc[2][2]=64 AGPR.
__global__ void __launch_bounds__(256, 3)
k_gemm(const u16* __restrict__ hk_h, const u16* __restrict__ w2t,
       const float* __restrict__ b2, const signed char* __restrict__ rank8,
       float* __restrict__ mats, int spin) {
  __shared__ signed char sRank[256][3];             // 768 B total LDS
  int t = threadIdx.x, wave = t >> 6, lane = t & 63;
  int l5 = lane >> 5, l31 = lane & 31;
  int mtile = blockIdx.x, n = blockIdx.y;
  int m0 = mtile * 256, n0 = n * 64;
  int s0 = n0 / 50;

  #pragma unroll
  for (int i = 0; i < 3; ++i) {
    int s = s0 + i;
    sRank[t][i] = (s < S_) ? rank8[((size_t)spin * B_ + m0 + t) * S_ + s]
                           : (signed char)-1;
  }

  const u16* aBase = hk_h + (size_t)(spin * 32 + mtile) * 131072 +
                     ((size_t)l5 * 256 + wave * 64 + l31) * 8;
  const u16* bBase = w2t + ((size_t)spin * NTB + n) * 32768 +
                     ((size_t)l5 * 64 + l31) * 8;

  f32x16 acc[2][2];
  #pragma unroll
  for (int rt = 0; rt < 2; ++rt)
    #pragma unroll
    for (int ct = 0; ct < 2; ++ct) acc[rt][ct] = (f32x16)(0.f);

  #pragma unroll 4
  for (int kc = 0; kc < 32; ++kc) {
    const u16* ap = aBase + (size_t)kc * 4096;
    const u16* bp = bBase + (size_t)kc * 1024;
    half8 ah[2], bf[2];
    ah[0] = *(const half8*)(ap);
    ah[1] = *(const half8*)(ap + 256);
    bf[0] = *(const half8*)(bp);
    bf[1] = *(const half8*)(bp + 256);
    #pragma unroll
    for (int rt = 0; rt < 2; ++rt)
      #pragma unroll
      for (int ct = 0; ct < 2; ++ct)
        acc[rt][ct] = __builtin_amdgcn_mfma_f32_32x32x16_f16(ah[rt], bf[ct], acc[rt][ct], 0, 0, 0);
  }

  const float invs = 1.0f / SCALE_H;
  #pragma unroll
  for (int ct = 0; ct < 2; ++ct) {
    int nc = n0 + ct * 32 + l31;
    if (nc < W2N) {
      int s = nc / 50;
      int j = nc - s * 50;
      int si = s - s0;
      float bias = b2[nc];
      #pragma unroll
      for (int rt = 0; rt < 2; ++rt) {
        #pragma unroll
        for (int reg = 0; reg < 16; ++reg) {
          int rr = wave * 64 + rt * 32 + (reg & 3) + 8 * (reg >> 2) + 4 * l5;
          int p = sRank[rr][si];
          if (p >= 0)
            mats[(size_t)(m0 + rr) * MMAT + p * MROW + j] = acc[rt][ct][reg] * invs + bias;
        }
      }
    }
  }
}

// ---- K3: 50x50 LU det, 1 matrix/wave, BATCHED readlane broadcasts ----
// Groups of 4 quads: 16 readlanes back-to-back, then 16 FMAs. The write->read
// distance hides the VALU->SGPR->VALU wait states that inflated R16-R20.
__global__ void __launch_bounds__(256, 1)
k_det(const float* __restrict__ mats, float* __restrict__ detw,
      float* __restrict__ out, int spin) {
  int t = threadIdx.x;
  int wave = t >> 6, lane = t & 63;
  int mb = blockIdx.x * 4 + wave;

  float4 row[13];
  if (lane < NF) {
    const float4* rp = (const float4*)(mats + (size_t)mb * MMAT + lane * MROW);
    #pragma unroll
    for (int q = 0; q < 13; ++q) row[q] = rp[q];
    row[12].z = 0.f;      // pad cols 50,51 (garbage in memory)
    row[12].w = 0.f;
  } else {
    #pragma unroll
    for (int q = 0; q < 13; ++q) row[q] = make_float4(0.f, 0.f, 0.f, 0.f);
  }

  double detd = 1.0;
  int parity = 0;
  int virt = lane;
  bool active = (lane < NF);
  #pragma unroll
  for (int p = 0; p < NF; ++p) {
    const int q_ = p >> 2, e_ = p & 3;
    float4 rq = row[q_];
    float cp = (e_ == 0) ? rq.x : (e_ == 1) ? rq.y : (e_ == 2) ? rq.z : rq.w;
    unsigned bits = __float_as_uint(fabsf(cp)) & 0xFFFFFFC0u;
    unsigned key = active ? (bits | (unsigned)lane) : 0u;
    #pragma unroll
    for (int mm = 32; mm >= 1; mm >>= 1) {
      unsigned o = (unsigned)__shfl_xor((int)key, mm);
      key = key > o ? key : o;
    }
    unsigned ukey = (unsigned)__builtin_amdgcn_readfirstlane((int)key);
    int pr = (int)(ukey & 63u);
    float v = rlane(cp, pr);
    if (ukey < 64u) v = 0.f;
    detd *= (double)v;
    int vp = __builtin_amdgcn_readlane(virt, p);
    unsigned long long bal = __ballot(virt == pr);
    int l = __ffsll((long long)bal) - 1;
    parity ^= (l != p) ? 1 : 0;
    virt = (lane == p) ? pr : ((lane == l) ? vp : virt);
    float invv = (v != 0.f) ? __builtin_amdgcn_rcpf(v) : 0.f;
    float mlt = (active && lane != pr) ? (cp * invv) : 0.f;
    active = active && (lane != pr);
    const int qs = (p + 1) >> 2;
    #pragma unroll
    for (int g = 0; g < 13; g += 4) {
      float bx[4], by[4], bz[4], bw[4];
      #pragma unroll
      for (int qq = 0; qq < 4; ++qq) {
        int q = g + qq;
        if (q >= qs && q < 13) {
          bx[qq] = rlane(row[q].x, pr);
          by[qq] = rlane(row[q].y, pr);
          bz[qq] = rlane(row[q].z, pr);
          bw[qq] = rlane(row[q].w, pr);
        }
      }
      #pragma unroll
      for (int qq = 0; qq < 4; ++qq) {
        int q = g + qq;
        if (q >= qs && q < 13) {
          row[q].x = fmaf(-mlt, bx[qq], row[q].x);
          row[q].y = fmaf(-mlt, by[qq], row[q].y);
          row[q].z = fmaf(-mlt, bz[qq], row[q].z);
          row[q].w = fmaf(-mlt, bw[qq], row[q].w);
        }
      }
    }
  }
  float det = (float)detd;
  if (parity) det = -det;
  if (lane == 0) {
    if (spin == 0) detw[mb] = det;
    else           out[mb]  = detw[mb] * det;
  }
}

extern "C" void kernel_launch(void* const* d_in, const int* in_sizes, int n_in,
                              void* d_out, int out_size, void* d_ws, size_t ws_size,
                              hipStream_t stream) {
  const float* cfg = (const float*)d_in[0];
  const float* W1u = (const float*)d_in[1];
  const float* b1u = (const float*)d_in[2];
  const float* W2u = (const float*)d_in[3];
  const float* b2u = (const float*)d_in[4];
  const float* W1d = (const float*)d_in[5];
  const float* b1d = (const float*)d_in[6];
  const float* W2d = (const float*)d_in[7];
  const float* b2d = (const float*)d_in[8];

  char* ws = (char*)d_ws;
  float* mats = (float*)ws;                 ws += (size_t)B_ * MMAT * 4;        // 85.2 MB
  u16*   hk_h = (u16*)ws;                   ws += (size_t)2 * B_ * H_ * 2;      // 16.8 MB
  u16*   w2t  = (u16*)ws;                   ws += (size_t)2 * NTB * 32768 * 2;  // 10.4 MB
  signed char* rank8 = (signed char*)ws;    ws += (size_t)2 * B_ * S_;          // 1.64 MB
  float* detw = (float*)ws;
  float* out  = (float*)d_out;

  k_prep  <<<dim3(NTB, 32, 2), 256, 0, stream>>>(W2u, W2d, w2t);
  k_hidden<<<dim3(B_, 2), 256, 0, stream>>>(cfg, W1u, b1u, W1d, b1d, hk_h, rank8);
  for (int spin = 0; spin < 2; ++spin) {
    const float* b2 = spin ? b2d : b2u;
    k_gemm<<<dim3(32, NTB), 256, 0, stream>>>(hk_h, w2t, b2, rank8, mats, spin);
    k_det <<<B_ / 4, 256, 0, stream>>>(mats, detw, out, spin);
  }
}

// Round 22
// 350.680 us; speedup vs baseline: 2.5231x; 2.5231x over previous
//
#include <hip/hip_runtime.h>

// B=8192, S=100, H=512, NF=50 filled/spin. out[b] = det_up * det_dn.
//   k_prep  : W2 -> fp16 fragment-image [spin][ntile64][kc][ko][64][8] (unscaled)
//   k_hidden: h rows -> single fp16 fragment-image slab (x256) + rank8
//   k_gemm  : 256x64 block tile, wave 64x64, acc[2][2], 1-product fp16 MFMA,
//             direct global->VGPR fragments, no LDS/barriers, unroll 4.
//   k_det   : 50x50 LU, 1 matrix/wave, rcpf, readlane broadcasts in quad-PAIRS
//             with NAMED scalar temps (round-22: R21's conditionally-written
//             arrays went to scratch, 1.7GB writes; pairs with compile-time
//             conditions keep everything in registers while giving the
//             readlane->fma write-to-read distance ~8 insts to cover the
//             VALU->SGPR->VALU hazard window).
// mats layout: row stride 52 floats, matrix stride 2600.

#define B_   8192
#define S_   100
#define H_   512
#define NF   50
#define W2N  5000
#define NTB  79            // 64-col tiles over 5000 (+56 pad)
#define MROW 52
#define MMAT 2600
#define SCALE_H 256.0f

typedef _Float16 half8 __attribute__((ext_vector_type(8)));
typedef float f32x16 __attribute__((ext_vector_type(16)));
typedef unsigned short u16;
typedef unsigned int u32;

__device__ __forceinline__ u16 f2h(float x) {
  _Float16 h = (_Float16)x;
  return __builtin_bit_cast(u16, h);
}
__device__ __forceinline__ float rlane(float x, int sl) {
  return __builtin_bit_cast(float,
      __builtin_amdgcn_readlane(__builtin_bit_cast(int, x), sl));
}

// ---- K0: W2 -> w2t[spin][n][kc][ko][64][8] fp16, cols >=5000 zero ----
__global__ void k_prep(const float* __restrict__ W2u, const float* __restrict__ W2d,
                       u16* __restrict__ w2t) {
  __shared__ float sT[16][65];
  int n = blockIdx.x, kc = blockIdx.y, spin = blockIdx.z, t = threadIdx.x;
  const float* W2 = spin ? W2d : W2u;
  #pragma unroll
  for (int i = 0; i < 4; ++i) {
    int idx = i * 256 + t;
    int r = idx >> 6, c = idx & 63;
    int nc = n * 64 + c;
    sT[r][c] = (nc < W2N) ? W2[(size_t)(kc * 16 + r) * W2N + nc] : 0.f;
  }
  __syncthreads();
  if (t < 128) {
    int ko = t >> 6, c = t & 63;
    __align__(16) u16 hb[8];
    #pragma unroll
    for (int j = 0; j < 8; ++j) hb[j] = f2h(sT[ko * 8 + j][c]);
    u16* dst = w2t + (((size_t)spin * NTB + n) * 32 + kc) * 1024 +
               (ko * 64 + c) * 8;
    *(uint4*)dst = *(const uint4*)&hb[0];
  }
}

// ---- K1: ballot-rank + h = relu(sum W1 rows + b1) -> fp16 slab + rank8 ----
__global__ void k_hidden(const float* __restrict__ cfg, const float* __restrict__ W1u,
                         const float* __restrict__ b1u, const float* __restrict__ W1d,
                         const float* __restrict__ b1d, u16* __restrict__ hk_h,
                         signed char* __restrict__ rank8) {
  __shared__ int sFilled[NF];
  __shared__ unsigned long long sM0;
  __shared__ u16 sHv[512];
  int b = blockIdx.x, spin = blockIdx.y, t = threadIdx.x;
  const float* W1 = spin ? W1d : W1u;
  const float* b1 = spin ? b1d : b1u;
  bool f = (t < S_) ? (cfg[(size_t)b * 200 + spin * 100 + t] > 0.5f) : false;
  unsigned long long m = __ballot(f);
  if (t == 0) sM0 = m;
  __syncthreads();
  int r = -1;
  if (f) {
    int lane = t & 63;
    int below = __popcll(m & ((1ULL << lane) - 1ULL));
    r = (t < 64) ? below : (__popcll(sM0) + below);
    sFilled[r] = t;
  }
  if (t < S_) rank8[((size_t)spin * B_ + b) * S_ + t] = (signed char)r;
  __syncthreads();
  float a0 = b1[t], a1 = b1[t + 256];
  #pragma unroll 5
  for (int i = 0; i < NF; ++i) {
    const float* w = W1 + (size_t)sFilled[i] * H_;
    a0 += w[t];
    a1 += w[t + 256];
  }
  a0 = fmaxf(a0, 0.f) * SCALE_H;
  a1 = fmaxf(a1, 0.f) * SCALE_H;
  sHv[t] = f2h(a0);
  sHv[t + 256] = f2h(a1);
  __syncthreads();
  int mtile = b >> 8, rr = b & 255;
  if (t < 64) {
    int kc = t >> 1, ko = t & 1;       // k-octet t of 64
    size_t off = ((((size_t)spin * 32 + mtile) * 32 + kc) * 2 + ko) * 2048 + rr * 8;
    *(uint4*)(hk_h + off) = *(const uint4*)&sHv[t * 8];
  }
}

// ---- K2: dense 256x64 GEMM, 1-product fp16, direct global->VGPR fragments ----
// grid (32 mtile, 79 ntile), block 256 = 4 waves stacked in M. acc[2][2]=64 AGPR.
__global__ void __launch_bounds__(256, 3)
k_gemm(const u16* __restrict__ hk_h, const u16* __restrict__ w2t,
       const float* __restrict__ b2, const signed char* __restrict__ rank8,
       float* __restrict__ mats, int spin) {
  __shared__ signed char sRank[256][3];             // 768 B total LDS
  int t = threadIdx.x, wave = t >> 6, lane = t & 63;
  int l5 = lane >> 5, l31 = lane & 31;
  int mtile = blockIdx.x, n = blockIdx.y;
  int m0 = mtile * 256, n0 = n * 64;
  int s0 = n0 / 50;

  #pragma unroll
  for (int i = 0; i < 3; ++i) {
    int s = s0 + i;
    sRank[t][i] = (s < S_) ? rank8[((size_t)spin * B_ + m0 + t) * S_ + s]
                           : (signed char)-1;
  }

  const u16* aBase = hk_h + (size_t)(spin * 32 + mtile) * 131072 +
                     ((size_t)l5 * 256 + wave * 64 + l31) * 8;
  const u16* bBase = w2t + ((size_t)spin * NTB + n) * 32768 +
                     ((size_t)l5 * 64 + l31) * 8;

  f32x16 acc[2][2];
  #pragma unroll
  for (int rt = 0; rt < 2; ++rt)
    #pragma unroll
    for (int ct = 0; ct < 2; ++ct) acc[rt][ct] = (f32x16)(0.f);

  #pragma unroll 4
  for (int kc = 0; kc < 32; ++kc) {
    const u16* ap = aBase + (size_t)kc * 4096;
    const u16* bp = bBase + (size_t)kc * 1024;
    half8 ah[2], bf[2];
    ah[0] = *(const half8*)(ap);
    ah[1] = *(const half8*)(ap + 256);
    bf[0] = *(const half8*)(bp);
    bf[1] = *(const half8*)(bp + 256);
    #pragma unroll
    for (int rt = 0; rt < 2; ++rt)
      #pragma unroll
      for (int ct = 0; ct < 2; ++ct)
        acc[rt][ct] = __builtin_amdgcn_mfma_f32_32x32x16_f16(ah[rt], bf[ct], acc[rt][ct], 0, 0, 0);
  }

  const float invs = 1.0f / SCALE_H;
  #pragma unroll
  for (int ct = 0; ct < 2; ++ct) {
    int nc = n0 + ct * 32 + l31;
    if (nc < W2N) {
      int s = nc / 50;
      int j = nc - s * 50;
      int si = s - s0;
      float bias = b2[nc];
      #pragma unroll
      for (int rt = 0; rt < 2; ++rt) {
        #pragma unroll
        for (int reg = 0; reg < 16; ++reg) {
          int rr = wave * 64 + rt * 32 + (reg & 3) + 8 * (reg >> 2) + 4 * l5;
          int p = sRank[rr][si];
          if (p >= 0)
            mats[(size_t)(m0 + rr) * MMAT + p * MROW + j] = acc[rt][ct][reg] * invs + bias;
        }
      }
    }
  }
}

// ---- K3: 50x50 LU det, 1 matrix/wave, quad-pair readlane broadcasts ----
__global__ void __launch_bounds__(256, 1)
k_det(const float* __restrict__ mats, float* __restrict__ detw,
      float* __restrict__ out, int spin) {
  int t = threadIdx.x;
  int wave = t >> 6, lane = t & 63;
  int mb = blockIdx.x * 4 + wave;

  float4 row[13];
  if (lane < NF) {
    const float4* rp = (const float4*)(mats + (size_t)mb * MMAT + lane * MROW);
    #pragma unroll
    for (int q = 0; q < 13; ++q) row[q] = rp[q];
    row[12].z = 0.f;      // pad cols 50,51 (garbage in memory)
    row[12].w = 0.f;
  } else {
    #pragma unroll
    for (int q = 0; q < 13; ++q) row[q] = make_float4(0.f, 0.f, 0.f, 0.f);
  }

  double detd = 1.0;
  int parity = 0;
  int virt = lane;
  bool active = (lane < NF);
  #pragma unroll
  for (int p = 0; p < NF; ++p) {
    const int q_ = p >> 2, e_ = p & 3;
    float4 rq = row[q_];
    float cp = (e_ == 0) ? rq.x : (e_ == 1) ? rq.y : (e_ == 2) ? rq.z : rq.w;
    unsigned bits = __float_as_uint(fabsf(cp)) & 0xFFFFFFC0u;
    unsigned key = active ? (bits | (unsigned)lane) : 0u;
    #pragma unroll
    for (int mm = 32; mm >= 1; mm >>= 1) {
      unsigned o = (unsigned)__shfl_xor((int)key, mm);
      key = key > o ? key : o;
    }
    unsigned ukey = (unsigned)__builtin_amdgcn_readfirstlane((int)key);
    int pr = (int)(ukey & 63u);
    float v = rlane(cp, pr);
    if (ukey < 64u) v = 0.f;
    detd *= (double)v;
    int vp = __builtin_amdgcn_readlane(virt, p);
    unsigned long long bal = __ballot(virt == pr);
    int l = __ffsll((long long)bal) - 1;
    parity ^= (l != p) ? 1 : 0;
    virt = (lane == p) ? pr : ((lane == l) ? vp : virt);
    float invv = (v != 0.f) ? __builtin_amdgcn_rcpf(v) : 0.f;
    float mlt = (active && lane != pr) ? (cp * invv) : 0.f;
    active = active && (lane != pr);
    const int qs = (p + 1) >> 2;
    // quad pairs: 8 readlanes back-to-back, then 8 FMAs (named temps only;
    // all conditions fold at unroll time -> pure register code)
    #pragma unroll
    for (int q = qs; q < 13; q += 2) {
      float ax = rlane(row[q].x, pr);
      float ay = rlane(row[q].y, pr);
      float az = rlane(row[q].z, pr);
      float aw = rlane(row[q].w, pr);
      float cx = 0.f, cy = 0.f, cz = 0.f, cw = 0.f;
      if (q + 1 < 13) {
        cx = rlane(row[q + 1].x, pr);
        cy = rlane(row[q + 1].y, pr);
        cz = rlane(row[q + 1].z, pr);
        cw = rlane(row[q + 1].w, pr);
      }
      row[q].x = fmaf(-mlt, ax, row[q].x);
      row[q].y = fmaf(-mlt, ay, row[q].y);
      row[q].z = fmaf(-mlt, az, row[q].z);
      row[q].w = fmaf(-mlt, aw, row[q].w);
      if (q + 1 < 13) {
        row[q + 1].x = fmaf(-mlt, cx, row[q + 1].x);
        row[q + 1].y = fmaf(-mlt, cy, row[q + 1].y);
        row[q + 1].z = fmaf(-mlt, cz, row[q + 1].z);
        row[q + 1].w = fmaf(-mlt, cw, row[q + 1].w);
      }
    }
  }
  float det = (float)detd;
  if (parity) det = -det;
  if (lane == 0) {
    if (spin == 0) detw[mb] = det;
    else           out[mb]  = detw[mb] * det;
  }
}

extern "C" void kernel_launch(void* const* d_in, const int* in_sizes, int n_in,
                              void* d_out, int out_size, void* d_ws, size_t ws_size,
                              hipStream_t stream) {
  const float* cfg = (const float*)d_in[0];
  const float* W1u = (const float*)d_in[1];
  const float* b1u = (const float*)d_in[2];
  const float* W2u = (const float*)d_in[3];
  const float* b2u = (const float*)d_in[4];
  const float* W1d = (const float*)d_in[5];
  const float* b1d = (const float*)d_in[6];
  const float* W2d = (const float*)d_in[7];
  const float* b2d = (const float*)d_in[8];

  char* ws = (char*)d_ws;
  float* mats = (float*)ws;                 ws += (size_t)B_ * MMAT * 4;        // 85.2 MB
  u16*   hk_h = (u16*)ws;                   ws += (size_t)2 * B_ * H_ * 2;      // 16.8 MB
  u16*   w2t  = (u16*)ws;                   ws += (size_t)2 * NTB * 32768 * 2;  // 10.4 MB
  signed char* rank8 = (signed char*)ws;    ws += (size_t)2 * B_ * S_;          // 1.64 MB
  float* detw = (float*)ws;
  float* out  = (float*)d_out;

  k_prep  <<<dim3(NTB, 32, 2), 256, 0, stream>>>(W2u, W2d, w2t);
  k_hidden<<<dim3(B_, 2), 256, 0, stream>>>(cfg, W1u, b1u, W1d, b1d, hk_h, rank8);
  for (int spin = 0; spin < 2; ++spin) {
    const float* b2 = spin ? b2d : b2u;
    k_gemm<<<dim3(32, NTB), 256, 0, stream>>>(hk_h, w2t, b2, rank8, mats, spin);
    k_det <<<B_ / 4, 256, 0, stream>>>(mats, detw, out, spin);
  }
}